// Round 1
// baseline (158.722 us; speedup 1.0000x reference)
//
#include <hip/hip_runtime.h>

#define B 4
#define T 256
#define S 512
#define H 512

// ---------------------------------------------------------------------------
// tanh via native exp + rcp (avoid IEEE fdiv sequence; no -ffast-math assumed)
// tanh(x) = 1 - 2/(exp(2x)+1).  exp->inf => 1, exp->0 => -1: saturates safely.
// ---------------------------------------------------------------------------
__device__ __forceinline__ float vtanh(float q, float k) {
    float e = __expf(2.0f * (q + k));
    return 1.0f - 2.0f * __builtin_amdgcn_rcpf(e + 1.0f);
}

__device__ __forceinline__ float dot_tanh(float4 v, float4 q, float4 k) {
    return v.x * vtanh(q.x, k.x) + v.y * vtanh(q.y, k.y) +
           v.z * vtanh(q.z, k.z) + v.w * vtanh(q.w, k.w);
}

// ---------------------------------------------------------------------------
// K1: fused projection GEMM.  C[m,n] = sum_k A[m,k]*W[n,k] + bias[n]
// Combined M: rows [0,1024) -> q (A=dh, W1,b1), rows [1024,3072) -> k (enc, W2,b2)
// 64x64 tile, BK=16, 4x4 micro-tile per thread, 256 threads.
// ---------------------------------------------------------------------------
__global__ __launch_bounds__(256) void proj_gemm(
    const float* __restrict__ dh, const float* __restrict__ enc,
    const float* __restrict__ W1, const float* __restrict__ b1,
    const float* __restrict__ W2, const float* __restrict__ b2,
    float* __restrict__ qout, float* __restrict__ kout)
{
    __shared__ float As[16][64];
    __shared__ float Ws[16][64];

    const int tid = threadIdx.x;
    const int nTile = blockIdx.x;   // 0..7
    const int mTile = blockIdx.y;   // 0..47

    const float* A; const float* W; const float* bias; float* Cout;
    int mbase;
    if (mTile < 16) { A = dh;  W = W1; bias = b1; Cout = qout; mbase = mTile * 64; }
    else            { A = enc; W = W2; bias = b2; Cout = kout; mbase = (mTile - 16) * 64; }
    const int n0 = nTile * 64;

    const int tn = tid & 15;        // n micro index
    const int tm = tid >> 4;        // m micro index
    const int lr = tid >> 2;        // staging row 0..63
    const int lc = tid & 3;         // staging float4 chunk 0..3

    float acc[4][4] = {};

    for (int kc = 0; kc < H; kc += 16) {
        float4 a4 = *(const float4*)&A[(size_t)(mbase + lr) * H + kc + lc * 4];
        float4 w4 = *(const float4*)&W[(size_t)(n0 + lr)   * H + kc + lc * 4];
        __syncthreads();
        As[lc * 4 + 0][lr] = a4.x; As[lc * 4 + 1][lr] = a4.y;
        As[lc * 4 + 2][lr] = a4.z; As[lc * 4 + 3][lr] = a4.w;
        Ws[lc * 4 + 0][lr] = w4.x; Ws[lc * 4 + 1][lr] = w4.y;
        Ws[lc * 4 + 2][lr] = w4.z; Ws[lc * 4 + 3][lr] = w4.w;
        __syncthreads();
        #pragma unroll
        for (int kk = 0; kk < 16; ++kk) {
            float4 av = *(const float4*)&As[kk][tm * 4];
            float4 wv = *(const float4*)&Ws[kk][tn * 4];
            float am[4] = {av.x, av.y, av.z, av.w};
            float wn[4] = {wv.x, wv.y, wv.z, wv.w};
            #pragma unroll
            for (int i = 0; i < 4; ++i)
                #pragma unroll
                for (int j = 0; j < 4; ++j)
                    acc[i][j] += am[i] * wn[j];
        }
    }

    float4 bv = *(const float4*)&bias[n0 + tn * 4];
    #pragma unroll
    for (int i = 0; i < 4; ++i) {
        float4 o;
        o.x = acc[i][0] + bv.x; o.y = acc[i][1] + bv.y;
        o.z = acc[i][2] + bv.z; o.w = acc[i][3] + bv.w;
        *(float4*)&Cout[(size_t)(mbase + tm * 4 + i) * H + n0 + tn * 4] = o;
    }
}

// ---------------------------------------------------------------------------
// K2: scores[b,t,s] = sum_h V[h]*tanh(q[b,t,h]+k[b,s,h]) + bV
// One wave per s (16 s per wave), 8 t-rows per block in registers,
// 64 lanes split H (8 floats/lane as 2 float4, coalesced k loads).
// ---------------------------------------------------------------------------
__global__ __launch_bounds__(256) void score_kernel(
    const float* __restrict__ qbuf, const float* __restrict__ kbuf,
    const float* __restrict__ Vp, const float* __restrict__ bVp,
    float* __restrict__ scores)
{
    const int b  = blockIdx.z;
    const int t0 = blockIdx.y * 8;
    const int s0 = blockIdx.x * 64;
    const int lane = threadIdx.x & 63;
    const int w    = threadIdx.x >> 6;
    const float bV = bVp[0];
    const int h0 = lane * 4;

    float4 va = *(const float4*)&Vp[h0];
    float4 vb = *(const float4*)&Vp[h0 + 256];

    float4 qa[8], qb[8];
    #pragma unroll
    for (int tt = 0; tt < 8; ++tt) {
        const float* qr = qbuf + (size_t)(b * T + t0 + tt) * H;
        qa[tt] = *(const float4*)&qr[h0];
        qb[tt] = *(const float4*)&qr[h0 + 256];
    }

    #pragma unroll 1
    for (int i = 0; i < 16; ++i) {
        const int s = s0 + w * 16 + i;
        const float* kr = kbuf + (size_t)(b * S + s) * H;
        float4 ka = *(const float4*)&kr[h0];
        float4 kb = *(const float4*)&kr[h0 + 256];

        float acc[8];
        #pragma unroll
        for (int tt = 0; tt < 8; ++tt)
            acc[tt] = dot_tanh(va, qa[tt], ka) + dot_tanh(vb, qb[tt], kb);

        #pragma unroll
        for (int tt = 0; tt < 8; ++tt) {
            #pragma unroll
            for (int off = 32; off; off >>= 1)
                acc[tt] += __shfl_xor(acc[tt], off);
        }

        if (lane == 0) {
            #pragma unroll
            for (int tt = 0; tt < 8; ++tt)
                scores[(size_t)(b * T + t0 + tt) * S + s] = acc[tt] + bV;
        }
    }
}

// ---------------------------------------------------------------------------
// K3: softmax over s + context = attn @ enc.  Block per 4 t-rows.
// ---------------------------------------------------------------------------
__global__ __launch_bounds__(256) void softmax_ctx(
    const float* __restrict__ scores, const float* __restrict__ enc,
    float* __restrict__ out)
{
    __shared__ float attn[4][S];
    __shared__ float red[4];

    const int b  = blockIdx.y;
    const int t0 = blockIdx.x * 4;
    const int tid  = threadIdx.x;
    const int lane = tid & 63;
    const int w    = tid >> 6;

    for (int tt = 0; tt < 4; ++tt) {
        const float* srow = scores + (size_t)(b * T + t0 + tt) * S;
        float s1 = srow[tid];
        float s2 = srow[tid + 256];

        // block max
        float m = fmaxf(s1, s2);
        #pragma unroll
        for (int off = 32; off; off >>= 1) m = fmaxf(m, __shfl_xor(m, off));
        if (lane == 0) red[w] = m;
        __syncthreads();
        m = fmaxf(fmaxf(red[0], red[1]), fmaxf(red[2], red[3]));
        __syncthreads();

        float e1 = __expf(s1 - m);
        float e2 = __expf(s2 - m);

        // block sum
        float sum = e1 + e2;
        #pragma unroll
        for (int off = 32; off; off >>= 1) sum += __shfl_xor(sum, off);
        if (lane == 0) red[w] = sum;
        __syncthreads();
        sum = red[0] + red[1] + red[2] + red[3];
        __syncthreads();

        float inv = __builtin_amdgcn_rcpf(sum);
        attn[tt][tid]       = e1 * inv;
        attn[tt][tid + 256] = e2 * inv;
    }
    __syncthreads();

    float c0[4] = {0.f, 0.f, 0.f, 0.f};
    float c1[4] = {0.f, 0.f, 0.f, 0.f};
    for (int s = 0; s < S; ++s) {
        float e0 = enc[(size_t)(b * S + s) * H + tid];
        float e1 = enc[(size_t)(b * S + s) * H + tid + 256];
        #pragma unroll
        for (int tt = 0; tt < 4; ++tt) {
            float a = attn[tt][s];
            c0[tt] += a * e0;
            c1[tt] += a * e1;
        }
    }
    #pragma unroll
    for (int tt = 0; tt < 4; ++tt) {
        out[(size_t)(b * T + t0 + tt) * H + tid]       = c0[tt];
        out[(size_t)(b * T + t0 + tt) * H + tid + 256] = c1[tt];
    }
}

extern "C" void kernel_launch(void* const* d_in, const int* in_sizes, int n_in,
                              void* d_out, int out_size, void* d_ws, size_t ws_size,
                              hipStream_t stream) {
    const float* dh  = (const float*)d_in[0];
    const float* enc = (const float*)d_in[1];
    const float* W1  = (const float*)d_in[2];
    const float* b1  = (const float*)d_in[3];
    const float* W2  = (const float*)d_in[4];
    const float* b2  = (const float*)d_in[5];
    const float* V   = (const float*)d_in[6];
    const float* bV  = (const float*)d_in[7];

    float* ws   = (float*)d_ws;
    float* qbuf = ws;                                  // B*T*H = 524288
    float* kbuf = qbuf + (size_t)B * T * H;            // B*S*H = 1048576
    float* sbuf = kbuf + (size_t)B * S * H;            // B*T*S = 524288

    dim3 blk(256);
    proj_gemm  <<<dim3(8, 48),    blk, 0, stream>>>(dh, enc, W1, b1, W2, b2, qbuf, kbuf);
    score_kernel<<<dim3(8, 32, 4), blk, 0, stream>>>(qbuf, kbuf, V, bV, sbuf);
    softmax_ctx<<<dim3(64, 4),    blk, 0, stream>>>(sbuf, enc, (float*)d_out);
}

// Round 2
// 127.506 us; speedup vs baseline: 1.2448x; 1.2448x over previous
//
#include <hip/hip_runtime.h>

#define B 4
#define T 256
#define S 512
#define H 512

// 2 * log2(e): q,k are prescaled by this so tanh needs only a bare v_exp_f32.
#define PRESCALE 2.8853900817779268f

#if __has_builtin(__builtin_amdgcn_exp2f)
#define EXP2(x) __builtin_amdgcn_exp2f(x)
#else
#define EXP2(x) exp2f(x)
#endif

// ---------------------------------------------------------------------------
// K1: fused projection GEMM.  C[m,n] = (sum_k A[m,k]*W[n,k] + bias[n]) * PRESCALE
// Combined M: rows [0,1024) -> q (A=dh, W1,b1), rows [1024,3072) -> k (enc, W2,b2)
// 64x64 tile, BK=16, 4x4 micro-tile per thread, 256 threads.
// ---------------------------------------------------------------------------
__global__ __launch_bounds__(256) void proj_gemm(
    const float* __restrict__ dh, const float* __restrict__ enc,
    const float* __restrict__ W1, const float* __restrict__ b1,
    const float* __restrict__ W2, const float* __restrict__ b2,
    float* __restrict__ qout, float* __restrict__ kout)
{
    __shared__ float As[16][64];
    __shared__ float Ws[16][64];

    const int tid = threadIdx.x;
    const int nTile = blockIdx.x;   // 0..7
    const int mTile = blockIdx.y;   // 0..47

    const float* A; const float* W; const float* bias; float* Cout;
    int mbase;
    if (mTile < 16) { A = dh;  W = W1; bias = b1; Cout = qout; mbase = mTile * 64; }
    else            { A = enc; W = W2; bias = b2; Cout = kout; mbase = (mTile - 16) * 64; }
    const int n0 = nTile * 64;

    const int tn = tid & 15;        // n micro index
    const int tm = tid >> 4;        // m micro index
    const int lr = tid >> 2;        // staging row 0..63
    const int lc = tid & 3;         // staging float4 chunk 0..3

    float acc[4][4] = {};

    for (int kc = 0; kc < H; kc += 16) {
        float4 a4 = *(const float4*)&A[(size_t)(mbase + lr) * H + kc + lc * 4];
        float4 w4 = *(const float4*)&W[(size_t)(n0 + lr)   * H + kc + lc * 4];
        __syncthreads();
        As[lc * 4 + 0][lr] = a4.x; As[lc * 4 + 1][lr] = a4.y;
        As[lc * 4 + 2][lr] = a4.z; As[lc * 4 + 3][lr] = a4.w;
        Ws[lc * 4 + 0][lr] = w4.x; Ws[lc * 4 + 1][lr] = w4.y;
        Ws[lc * 4 + 2][lr] = w4.z; Ws[lc * 4 + 3][lr] = w4.w;
        __syncthreads();
        #pragma unroll
        for (int kk = 0; kk < 16; ++kk) {
            float4 av = *(const float4*)&As[kk][tm * 4];
            float4 wv = *(const float4*)&Ws[kk][tn * 4];
            float am[4] = {av.x, av.y, av.z, av.w};
            float wn[4] = {wv.x, wv.y, wv.z, wv.w};
            #pragma unroll
            for (int i = 0; i < 4; ++i)
                #pragma unroll
                for (int j = 0; j < 4; ++j)
                    acc[i][j] += am[i] * wn[j];
        }
    }

    float4 bv = *(const float4*)&bias[n0 + tn * 4];
    #pragma unroll
    for (int i = 0; i < 4; ++i) {
        float4 o;
        o.x = (acc[i][0] + bv.x) * PRESCALE;
        o.y = (acc[i][1] + bv.y) * PRESCALE;
        o.z = (acc[i][2] + bv.z) * PRESCALE;
        o.w = (acc[i][3] + bv.w) * PRESCALE;
        *(float4*)&Cout[(size_t)(mbase + tm * 4 + i) * H + n0 + tn * 4] = o;
    }
}

// ---------------------------------------------------------------------------
// K2: scores[b,t,s] = sum_h V[h]*tanh(q+k) + bV
//   with prescaled q,k:  = sum_h V[h] - sum_h 2V[h]*rcp(exp2(q'+k')+1) + bV
// Wave: 4 t-rows in registers, 4 s serially; 64 lanes split H (4 floats x2).
// Inner loop per element: v_add, v_exp, v_add, v_rcp, v_fmac  (3 VALU + 2 trans)
// ---------------------------------------------------------------------------
__global__ __launch_bounds__(256) void score_kernel(
    const float* __restrict__ qbuf, const float* __restrict__ kbuf,
    const float* __restrict__ Vp, const float* __restrict__ bVp,
    float* __restrict__ scores)
{
    const int lane = threadIdx.x & 63;
    const int w    = threadIdx.x >> 6;
    const int b    = blockIdx.z;
    const int t0   = blockIdx.y * 4;
    const int s0   = blockIdx.x * 16 + w * 4;
    const int h0   = lane * 4;
    const float bV = bVp[0];

    float4 va = *(const float4*)&Vp[h0];
    float4 vb = *(const float4*)&Vp[h0 + 256];
    // per-lane partial sum of V (reduces to full sum(V) across 64 lanes)
    const float pv = va.x + va.y + va.z + va.w + vb.x + vb.y + vb.z + vb.w;
    const float4 na = make_float4(-2.f * va.x, -2.f * va.y, -2.f * va.z, -2.f * va.w);
    const float4 nb = make_float4(-2.f * vb.x, -2.f * vb.y, -2.f * vb.z, -2.f * vb.w);

    float4 qa[4], qb[4];
    #pragma unroll
    for (int tt = 0; tt < 4; ++tt) {
        const float* qr = qbuf + (size_t)(b * T + t0 + tt) * H;
        qa[tt] = *(const float4*)&qr[h0];
        qb[tt] = *(const float4*)&qr[h0 + 256];
    }

    #pragma unroll 1
    for (int i = 0; i < 4; ++i) {
        const int s = s0 + i;
        const float* kr = kbuf + (size_t)(b * S + s) * H;
        float4 ka = *(const float4*)&kr[h0];
        float4 kb = *(const float4*)&kr[h0 + 256];

        float acc[4] = {pv, pv, pv, pv};
        #pragma unroll
        for (int tt = 0; tt < 4; ++tt) {
            float a = acc[tt];
            a = fmaf(na.x, __builtin_amdgcn_rcpf(EXP2(qa[tt].x + ka.x) + 1.0f), a);
            a = fmaf(na.y, __builtin_amdgcn_rcpf(EXP2(qa[tt].y + ka.y) + 1.0f), a);
            a = fmaf(na.z, __builtin_amdgcn_rcpf(EXP2(qa[tt].z + ka.z) + 1.0f), a);
            a = fmaf(na.w, __builtin_amdgcn_rcpf(EXP2(qa[tt].w + ka.w) + 1.0f), a);
            a = fmaf(nb.x, __builtin_amdgcn_rcpf(EXP2(qb[tt].x + kb.x) + 1.0f), a);
            a = fmaf(nb.y, __builtin_amdgcn_rcpf(EXP2(qb[tt].y + kb.y) + 1.0f), a);
            a = fmaf(nb.z, __builtin_amdgcn_rcpf(EXP2(qb[tt].z + kb.z) + 1.0f), a);
            a = fmaf(nb.w, __builtin_amdgcn_rcpf(EXP2(qb[tt].w + kb.w) + 1.0f), a);
            acc[tt] = a;
        }

        #pragma unroll
        for (int tt = 0; tt < 4; ++tt) {
            #pragma unroll
            for (int off = 32; off; off >>= 1)
                acc[tt] += __shfl_xor(acc[tt], off);
        }

        // all lanes hold the full sums now; lanes 0..3 store row t0+lane
        float out = acc[0];
        out = (lane == 1) ? acc[1] : out;
        out = (lane == 2) ? acc[2] : out;
        out = (lane == 3) ? acc[3] : out;
        if (lane < 4)
            scores[(size_t)(b * T + t0 + lane) * S + s] = out + bV;
    }
}

// ---------------------------------------------------------------------------
// K3: softmax over s + context = attn @ enc.  Block per 4 t-rows.
// ---------------------------------------------------------------------------
__global__ __launch_bounds__(256) void softmax_ctx(
    const float* __restrict__ scores, const float* __restrict__ enc,
    float* __restrict__ out)
{
    __shared__ float attn[4][S];
    __shared__ float red[4];

    const int b  = blockIdx.y;
    const int t0 = blockIdx.x * 4;
    const int tid  = threadIdx.x;
    const int lane = tid & 63;
    const int w    = tid >> 6;

    for (int tt = 0; tt < 4; ++tt) {
        const float* srow = scores + (size_t)(b * T + t0 + tt) * S;
        float s1 = srow[tid];
        float s2 = srow[tid + 256];

        // block max
        float m = fmaxf(s1, s2);
        #pragma unroll
        for (int off = 32; off; off >>= 1) m = fmaxf(m, __shfl_xor(m, off));
        if (lane == 0) red[w] = m;
        __syncthreads();
        m = fmaxf(fmaxf(red[0], red[1]), fmaxf(red[2], red[3]));
        __syncthreads();

        float e1 = __expf(s1 - m);
        float e2 = __expf(s2 - m);

        // block sum
        float sum = e1 + e2;
        #pragma unroll
        for (int off = 32; off; off >>= 1) sum += __shfl_xor(sum, off);
        if (lane == 0) red[w] = sum;
        __syncthreads();
        sum = red[0] + red[1] + red[2] + red[3];
        __syncthreads();

        float inv = __builtin_amdgcn_rcpf(sum);
        attn[tt][tid]       = e1 * inv;
        attn[tt][tid + 256] = e2 * inv;
    }
    __syncthreads();

    float c0[4] = {0.f, 0.f, 0.f, 0.f};
    float c1[4] = {0.f, 0.f, 0.f, 0.f};
    for (int s = 0; s < S; ++s) {
        float e0 = enc[(size_t)(b * S + s) * H + tid];
        float e1 = enc[(size_t)(b * S + s) * H + tid + 256];
        #pragma unroll
        for (int tt = 0; tt < 4; ++tt) {
            float a = attn[tt][s];
            c0[tt] += a * e0;
            c1[tt] += a * e1;
        }
    }
    #pragma unroll
    for (int tt = 0; tt < 4; ++tt) {
        out[(size_t)(b * T + t0 + tt) * H + tid]       = c0[tt];
        out[(size_t)(b * T + t0 + tt) * H + tid + 256] = c1[tt];
    }
}

extern "C" void kernel_launch(void* const* d_in, const int* in_sizes, int n_in,
                              void* d_out, int out_size, void* d_ws, size_t ws_size,
                              hipStream_t stream) {
    const float* dh  = (const float*)d_in[0];
    const float* enc = (const float*)d_in[1];
    const float* W1  = (const float*)d_in[2];
    const float* b1  = (const float*)d_in[3];
    const float* W2  = (const float*)d_in[4];
    const float* b2  = (const float*)d_in[5];
    const float* V   = (const float*)d_in[6];
    const float* bV  = (const float*)d_in[7];

    float* ws   = (float*)d_ws;
    float* qbuf = ws;                                  // B*T*H = 524288
    float* kbuf = qbuf + (size_t)B * T * H;            // B*S*H = 1048576
    float* sbuf = kbuf + (size_t)B * S * H;            // B*T*S = 524288

    dim3 blk(256);
    proj_gemm   <<<dim3(8, 48),     blk, 0, stream>>>(dh, enc, W1, b1, W2, b2, qbuf, kbuf);
    score_kernel<<<dim3(32, 64, 4), blk, 0, stream>>>(qbuf, kbuf, V, bV, sbuf);
    softmax_ctx <<<dim3(64, 4),     blk, 0, stream>>>(sbuf, enc, (float*)d_out);
}

// Round 3
// 113.534 us; speedup vs baseline: 1.3980x; 1.1231x over previous
//
#include <hip/hip_runtime.h>

#define B 4
#define T 256
#define S 512
#define H 512

// 2 * log2(e): projections are prescaled so exp2 replaces exp.
#define PRESCALE 2.8853900817779268f

#if __has_builtin(__builtin_amdgcn_exp2f)
#define EXP2(x) __builtin_amdgcn_exp2f(x)
#else
#define EXP2(x) exp2f(x)
#endif

// ---------------------------------------------------------------------------
// K1: fused projection GEMM + exp epilogue.
//   out[m,n] = exp2( min( (sum_k A[m,k]*W[n,k] + bias[n]) * PRESCALE, 126 ) )
// Rows [0,1024) -> a = exp2(q') (A=dh,W1,b1); rows [1024,3072) -> b = exp2(k').
// 64x64 tile, BK=16, 4x4 micro-tile per thread, 256 threads.
// ---------------------------------------------------------------------------
__global__ __launch_bounds__(256) void proj_gemm(
    const float* __restrict__ dh, const float* __restrict__ enc,
    const float* __restrict__ W1, const float* __restrict__ b1,
    const float* __restrict__ W2, const float* __restrict__ b2,
    float* __restrict__ qout, float* __restrict__ kout)
{
    __shared__ float As[16][64];
    __shared__ float Ws[16][64];

    const int tid = threadIdx.x;
    const int nTile = blockIdx.x;   // 0..7
    const int mTile = blockIdx.y;   // 0..47

    const float* A; const float* W; const float* bias; float* Cout;
    int mbase;
    if (mTile < 16) { A = dh;  W = W1; bias = b1; Cout = qout; mbase = mTile * 64; }
    else            { A = enc; W = W2; bias = b2; Cout = kout; mbase = (mTile - 16) * 64; }
    const int n0 = nTile * 64;

    const int tn = tid & 15;        // n micro index
    const int tm = tid >> 4;        // m micro index
    const int lr = tid >> 2;        // staging row 0..63
    const int lc = tid & 3;         // staging float4 chunk 0..3

    float acc[4][4] = {};

    for (int kc = 0; kc < H; kc += 16) {
        float4 a4 = *(const float4*)&A[(size_t)(mbase + lr) * H + kc + lc * 4];
        float4 w4 = *(const float4*)&W[(size_t)(n0 + lr)   * H + kc + lc * 4];
        __syncthreads();
        As[lc * 4 + 0][lr] = a4.x; As[lc * 4 + 1][lr] = a4.y;
        As[lc * 4 + 2][lr] = a4.z; As[lc * 4 + 3][lr] = a4.w;
        Ws[lc * 4 + 0][lr] = w4.x; Ws[lc * 4 + 1][lr] = w4.y;
        Ws[lc * 4 + 2][lr] = w4.z; Ws[lc * 4 + 3][lr] = w4.w;
        __syncthreads();
        #pragma unroll
        for (int kk = 0; kk < 16; ++kk) {
            float4 av = *(const float4*)&As[kk][tm * 4];
            float4 wv = *(const float4*)&Ws[kk][tn * 4];
            float am[4] = {av.x, av.y, av.z, av.w};
            float wn[4] = {wv.x, wv.y, wv.z, wv.w};
            #pragma unroll
            for (int i = 0; i < 4; ++i)
                #pragma unroll
                for (int j = 0; j < 4; ++j)
                    acc[i][j] += am[i] * wn[j];
        }
    }

    float4 bv = *(const float4*)&bias[n0 + tn * 4];
    #pragma unroll
    for (int i = 0; i < 4; ++i) {
        float4 o;
        o.x = EXP2(fminf((acc[i][0] + bv.x) * PRESCALE, 126.f));
        o.y = EXP2(fminf((acc[i][1] + bv.y) * PRESCALE, 126.f));
        o.z = EXP2(fminf((acc[i][2] + bv.z) * PRESCALE, 126.f));
        o.w = EXP2(fminf((acc[i][3] + bv.w) * PRESCALE, 126.f));
        *(float4*)&Cout[(size_t)(mbase + tm * 4 + i) * H + n0 + tn * 4] = o;
    }
}

// ---------------------------------------------------------------------------
// K2: scores[b,t,s] = sum_h V[h]*tanh(q+k) + bV
//   tanh(q+k) = 1 - 2/(a*b + 1)  with a=exp2(q'), b=exp2(k') precomputed.
//   score = sum_h V[h] + sum_h (-2V[h]) * rcp(fma(a,b,1)) + bV
// Inner loop per element: v_fma, v_rcp, v_fmac  (2 VALU + 1 trans)
// Wave: 4 t-rows in registers, 4 s serially; 64 lanes split H (4 floats x2).
// ---------------------------------------------------------------------------
__global__ __launch_bounds__(256) void score_kernel(
    const float* __restrict__ abuf, const float* __restrict__ bbuf,
    const float* __restrict__ Vp, const float* __restrict__ bVp,
    float* __restrict__ scores)
{
    const int lane = threadIdx.x & 63;
    const int w    = threadIdx.x >> 6;
    const int b    = blockIdx.z;
    const int t0   = blockIdx.y * 4;
    const int s0   = blockIdx.x * 16 + w * 4;
    const int h0   = lane * 4;
    const float bV = bVp[0];

    float4 va = *(const float4*)&Vp[h0];
    float4 vb = *(const float4*)&Vp[h0 + 256];
    // per-lane partial sum of V (reduces to full sum(V) across 64 lanes)
    const float pv = va.x + va.y + va.z + va.w + vb.x + vb.y + vb.z + vb.w;
    const float4 na = make_float4(-2.f * va.x, -2.f * va.y, -2.f * va.z, -2.f * va.w);
    const float4 nb = make_float4(-2.f * vb.x, -2.f * vb.y, -2.f * vb.z, -2.f * vb.w);

    float4 qa[4], qb[4];
    #pragma unroll
    for (int tt = 0; tt < 4; ++tt) {
        const float* qr = abuf + (size_t)(b * T + t0 + tt) * H;
        qa[tt] = *(const float4*)&qr[h0];
        qb[tt] = *(const float4*)&qr[h0 + 256];
    }

    #pragma unroll 1
    for (int i = 0; i < 4; ++i) {
        const int s = s0 + i;
        const float* kr = bbuf + (size_t)(b * S + s) * H;
        float4 ka = *(const float4*)&kr[h0];
        float4 kb = *(const float4*)&kr[h0 + 256];

        float acc[4] = {pv, pv, pv, pv};
        #pragma unroll
        for (int tt = 0; tt < 4; ++tt) {
            float a = acc[tt];
            a = fmaf(na.x, __builtin_amdgcn_rcpf(fmaf(qa[tt].x, ka.x, 1.0f)), a);
            a = fmaf(na.y, __builtin_amdgcn_rcpf(fmaf(qa[tt].y, ka.y, 1.0f)), a);
            a = fmaf(na.z, __builtin_amdgcn_rcpf(fmaf(qa[tt].z, ka.z, 1.0f)), a);
            a = fmaf(na.w, __builtin_amdgcn_rcpf(fmaf(qa[tt].w, ka.w, 1.0f)), a);
            a = fmaf(nb.x, __builtin_amdgcn_rcpf(fmaf(qb[tt].x, kb.x, 1.0f)), a);
            a = fmaf(nb.y, __builtin_amdgcn_rcpf(fmaf(qb[tt].y, kb.y, 1.0f)), a);
            a = fmaf(nb.z, __builtin_amdgcn_rcpf(fmaf(qb[tt].z, kb.z, 1.0f)), a);
            a = fmaf(nb.w, __builtin_amdgcn_rcpf(fmaf(qb[tt].w, kb.w, 1.0f)), a);
            acc[tt] = a;
        }

        #pragma unroll
        for (int tt = 0; tt < 4; ++tt) {
            #pragma unroll
            for (int off = 32; off; off >>= 1)
                acc[tt] += __shfl_xor(acc[tt], off);
        }

        // all lanes hold the full sums now; lanes 0..3 store row t0+lane
        float out = acc[0];
        out = (lane == 1) ? acc[1] : out;
        out = (lane == 2) ? acc[2] : out;
        out = (lane == 3) ? acc[3] : out;
        if (lane < 4)
            scores[(size_t)(b * T + t0 + lane) * S + s] = out + bV;
    }
}

// ---------------------------------------------------------------------------
// K3: softmax over s + context = attn @ enc.  Block per 4 t-rows.
// ---------------------------------------------------------------------------
__global__ __launch_bounds__(256) void softmax_ctx(
    const float* __restrict__ scores, const float* __restrict__ enc,
    float* __restrict__ out)
{
    __shared__ float attn[4][S];
    __shared__ float red[4];

    const int b  = blockIdx.y;
    const int t0 = blockIdx.x * 4;
    const int tid  = threadIdx.x;
    const int lane = tid & 63;
    const int w    = tid >> 6;

    for (int tt = 0; tt < 4; ++tt) {
        const float* srow = scores + (size_t)(b * T + t0 + tt) * S;
        float s1 = srow[tid];
        float s2 = srow[tid + 256];

        // block max
        float m = fmaxf(s1, s2);
        #pragma unroll
        for (int off = 32; off; off >>= 1) m = fmaxf(m, __shfl_xor(m, off));
        if (lane == 0) red[w] = m;
        __syncthreads();
        m = fmaxf(fmaxf(red[0], red[1]), fmaxf(red[2], red[3]));
        __syncthreads();

        float e1 = __expf(s1 - m);
        float e2 = __expf(s2 - m);

        // block sum
        float sum = e1 + e2;
        #pragma unroll
        for (int off = 32; off; off >>= 1) sum += __shfl_xor(sum, off);
        if (lane == 0) red[w] = sum;
        __syncthreads();
        sum = red[0] + red[1] + red[2] + red[3];
        __syncthreads();

        float inv = __builtin_amdgcn_rcpf(sum);
        attn[tt][tid]       = e1 * inv;
        attn[tt][tid + 256] = e2 * inv;
    }
    __syncthreads();

    float c0[4] = {0.f, 0.f, 0.f, 0.f};
    float c1[4] = {0.f, 0.f, 0.f, 0.f};
    for (int s = 0; s < S; ++s) {
        float e0 = enc[(size_t)(b * S + s) * H + tid];
        float e1 = enc[(size_t)(b * S + s) * H + tid + 256];
        #pragma unroll
        for (int tt = 0; tt < 4; ++tt) {
            float a = attn[tt][s];
            c0[tt] += a * e0;
            c1[tt] += a * e1;
        }
    }
    #pragma unroll
    for (int tt = 0; tt < 4; ++tt) {
        out[(size_t)(b * T + t0 + tt) * H + tid]       = c0[tt];
        out[(size_t)(b * T + t0 + tt) * H + tid + 256] = c1[tt];
    }
}

extern "C" void kernel_launch(void* const* d_in, const int* in_sizes, int n_in,
                              void* d_out, int out_size, void* d_ws, size_t ws_size,
                              hipStream_t stream) {
    const float* dh  = (const float*)d_in[0];
    const float* enc = (const float*)d_in[1];
    const float* W1  = (const float*)d_in[2];
    const float* b1  = (const float*)d_in[3];
    const float* W2  = (const float*)d_in[4];
    const float* b2  = (const float*)d_in[5];
    const float* V   = (const float*)d_in[6];
    const float* bV  = (const float*)d_in[7];

    float* ws   = (float*)d_ws;
    float* abuf = ws;                                  // B*T*H = 524288 (exp2 of q')
    float* bbuf = abuf + (size_t)B * T * H;            // B*S*H = 1048576 (exp2 of k')
    float* sbuf = bbuf + (size_t)B * S * H;            // B*T*S = 524288

    dim3 blk(256);
    proj_gemm   <<<dim3(8, 48),     blk, 0, stream>>>(dh, enc, W1, b1, W2, b2, abuf, bbuf);
    score_kernel<<<dim3(32, 64, 4), blk, 0, stream>>>(abuf, bbuf, V, bV, sbuf);
    softmax_ctx <<<dim3(64, 4),     blk, 0, stream>>>(sbuf, enc, (float*)d_out);
}

// Round 4
// 109.616 us; speedup vs baseline: 1.4480x; 1.0357x over previous
//
#include <hip/hip_runtime.h>

#define B 4
#define T 256
#define S 512
#define H 512
#define H4 (H/4)          // 128
#define NCHUNK 4
#define HC (H/NCHUNK)     // 128 h per score chunk
#define BTS (B*T*S)       // 524288

// 2 * log2(e): projections are prescaled so exp2 replaces exp.
#define PRESCALE 2.8853900817779268f

#if __has_builtin(__builtin_amdgcn_exp2f)
#define EXP2(x) __builtin_amdgcn_exp2f(x)
#else
#define EXP2(x) exp2f(x)
#endif

// ---------------------------------------------------------------------------
// K1: fused projection GEMM + exp2 epilogue.
//   o[m,n] = exp2( min( (sum_k A[m,k]*W[n,k] + bias[n]) * PRESCALE, 126 ) )
// q-part (mTile<16): store row-major abuf[t][h]  (read by K2 as uniform scalars)
// k-part (mTile>=16): store transposed/packed bT4[b][h/4][s][4] via LDS transpose
// ---------------------------------------------------------------------------
__global__ __launch_bounds__(256) void proj_gemm(
    const float* __restrict__ dh, const float* __restrict__ enc,
    const float* __restrict__ W1, const float* __restrict__ b1,
    const float* __restrict__ W2, const float* __restrict__ b2,
    float* __restrict__ abuf, float* __restrict__ bT4)
{
    __shared__ float As[16][64];
    __shared__ float Ws[16][64];
    __shared__ float TT[64][68];   // transpose staging (68: 16B-aligned rows, low conflict)

    const int tid = threadIdx.x;
    const int nTile = blockIdx.x;   // 0..7
    const int mTile = blockIdx.y;   // 0..47

    const float* A; const float* W; const float* bias;
    int mbase;
    const bool is_q = (mTile < 16);
    if (is_q) { A = dh;  W = W1; bias = b1; mbase = mTile * 64; }
    else      { A = enc; W = W2; bias = b2; mbase = (mTile - 16) * 64; }
    const int n0 = nTile * 64;

    const int tn = tid & 15;        // n micro index
    const int tm = tid >> 4;        // m micro index
    const int lr = tid >> 2;        // staging row 0..63
    const int lc = tid & 3;         // staging float4 chunk 0..3

    float acc[4][4] = {};

    for (int kc = 0; kc < H; kc += 16) {
        float4 a4 = *(const float4*)&A[(size_t)(mbase + lr) * H + kc + lc * 4];
        float4 w4 = *(const float4*)&W[(size_t)(n0 + lr)   * H + kc + lc * 4];
        __syncthreads();
        As[lc * 4 + 0][lr] = a4.x; As[lc * 4 + 1][lr] = a4.y;
        As[lc * 4 + 2][lr] = a4.z; As[lc * 4 + 3][lr] = a4.w;
        Ws[lc * 4 + 0][lr] = w4.x; Ws[lc * 4 + 1][lr] = w4.y;
        Ws[lc * 4 + 2][lr] = w4.z; Ws[lc * 4 + 3][lr] = w4.w;
        __syncthreads();
        #pragma unroll
        for (int kk = 0; kk < 16; ++kk) {
            float4 av = *(const float4*)&As[kk][tm * 4];
            float4 wv = *(const float4*)&Ws[kk][tn * 4];
            float am[4] = {av.x, av.y, av.z, av.w};
            float wn[4] = {wv.x, wv.y, wv.z, wv.w};
            #pragma unroll
            for (int i = 0; i < 4; ++i)
                #pragma unroll
                for (int j = 0; j < 4; ++j)
                    acc[i][j] += am[i] * wn[j];
        }
    }

    float4 bv = *(const float4*)&bias[n0 + tn * 4];
    float bj[4] = {bv.x, bv.y, bv.z, bv.w};
    float o[4][4];
    #pragma unroll
    for (int i = 0; i < 4; ++i)
        #pragma unroll
        for (int j = 0; j < 4; ++j)
            o[i][j] = EXP2(fminf((acc[i][j] + bj[j]) * PRESCALE, 126.f));

    if (is_q) {
        #pragma unroll
        for (int i = 0; i < 4; ++i) {
            float4 ov = make_float4(o[i][0], o[i][1], o[i][2], o[i][3]);
            *(float4*)&abuf[(size_t)(mbase + tm * 4 + i) * H + n0 + tn * 4] = ov;
        }
    } else {
        // stage tile (s_local, h_local) into LDS, read out s-coalesced
        #pragma unroll
        for (int i = 0; i < 4; ++i) {
            float4 ov = make_float4(o[i][0], o[i][1], o[i][2], o[i][3]);
            *(float4*)&TT[tm * 4 + i][tn * 4] = ov;
        }
        __syncthreads();
        const int sl = tid & 63;            // s within tile
        const int hq = tid >> 6;            // 0..3
        const int sg = mbase + sl;          // global row 0..2047
        const int bb = sg >> 9;             // batch
        const int ss = sg & 511;            // s
        #pragma unroll
        for (int jj = 0; jj < 4; ++jj) {
            const int hl = jj * 16 + hq * 4;    // h_local, 16B aligned
            float4 v = *(const float4*)&TT[sl][hl];
            const int h = n0 + hl;
            *(float4*)&bT4[((size_t)(bb * H4 + (h >> 2)) * S + ss) * 4] = v;
        }
    }
}

// ---------------------------------------------------------------------------
// K2: score partials.  full score = sum_h V[h] - 2*sum_h V[h]*rcp(a*b+1) + bV
//   a = exp2(q') uniform per (t,h) -> scalar loads; b = exp2(k') lane = s.
// Wave: 4 t accumulators, 64 s (lanes), HC=128 h chunk.  NO cross-lane reduce.
// Inner per element: v_fma, v_rcp, v_fmac  (plus amortized 1 vload / 4h / 4t)
// ---------------------------------------------------------------------------
__global__ __launch_bounds__(256) void score_kernel(
    const float* __restrict__ abuf, const float* __restrict__ bT4,
    const float* __restrict__ Vp, const float* __restrict__ bVp,
    float* __restrict__ spart)
{
    const int tid  = threadIdx.x;
    const int lane = tid & 63;
    const int w    = tid >> 6;
    const int b    = blockIdx.z >> 2;
    const int c    = blockIdx.z & 3;           // h-chunk
    const int t0   = blockIdx.y * 16 + w * 4;
    const int s0   = blockIdx.x * 64;
    const int h0   = c * HC;

    // chunk-sum of V (all lanes end with full sum), + bV once (chunk 0)
    float pv = Vp[h0 + lane] + Vp[h0 + 64 + lane];
    #pragma unroll
    for (int off = 32; off; off >>= 1) pv += __shfl_xor(pv, off);
    if (c == 0) pv += bVp[0];

    // wave-uniform q-row bases -> scalar loads in the loop
    const float* a0 = abuf + __builtin_amdgcn_readfirstlane((b * T + t0 + 0) * H);
    const float* a1 = abuf + __builtin_amdgcn_readfirstlane((b * T + t0 + 1) * H);
    const float* a2 = abuf + __builtin_amdgcn_readfirstlane((b * T + t0 + 2) * H);
    const float* a3 = abuf + __builtin_amdgcn_readfirstlane((b * T + t0 + 3) * H);

    const float4* bp = (const float4*)bT4 + (size_t)(b * H4 + (h0 >> 2)) * S + s0 + lane;

    float acc0 = 0.f, acc1 = 0.f, acc2 = 0.f, acc3 = 0.f;

    #pragma unroll 4
    for (int h4 = 0; h4 < HC / 4; ++h4) {
        const int h = h0 + h4 * 4;
        float4 kb = bp[(size_t)h4 * S];
        float4 v4  = *(const float4*)&Vp[h];
        float4 qa0 = *(const float4*)&a0[h];
        float4 qa1 = *(const float4*)&a1[h];
        float4 qa2 = *(const float4*)&a2[h];
        float4 qa3 = *(const float4*)&a3[h];

        acc0 = fmaf(v4.x, __builtin_amdgcn_rcpf(fmaf(qa0.x, kb.x, 1.f)), acc0);
        acc0 = fmaf(v4.y, __builtin_amdgcn_rcpf(fmaf(qa0.y, kb.y, 1.f)), acc0);
        acc0 = fmaf(v4.z, __builtin_amdgcn_rcpf(fmaf(qa0.z, kb.z, 1.f)), acc0);
        acc0 = fmaf(v4.w, __builtin_amdgcn_rcpf(fmaf(qa0.w, kb.w, 1.f)), acc0);

        acc1 = fmaf(v4.x, __builtin_amdgcn_rcpf(fmaf(qa1.x, kb.x, 1.f)), acc1);
        acc1 = fmaf(v4.y, __builtin_amdgcn_rcpf(fmaf(qa1.y, kb.y, 1.f)), acc1);
        acc1 = fmaf(v4.z, __builtin_amdgcn_rcpf(fmaf(qa1.z, kb.z, 1.f)), acc1);
        acc1 = fmaf(v4.w, __builtin_amdgcn_rcpf(fmaf(qa1.w, kb.w, 1.f)), acc1);

        acc2 = fmaf(v4.x, __builtin_amdgcn_rcpf(fmaf(qa2.x, kb.x, 1.f)), acc2);
        acc2 = fmaf(v4.y, __builtin_amdgcn_rcpf(fmaf(qa2.y, kb.y, 1.f)), acc2);
        acc2 = fmaf(v4.z, __builtin_amdgcn_rcpf(fmaf(qa2.z, kb.z, 1.f)), acc2);
        acc2 = fmaf(v4.w, __builtin_amdgcn_rcpf(fmaf(qa2.w, kb.w, 1.f)), acc2);

        acc3 = fmaf(v4.x, __builtin_amdgcn_rcpf(fmaf(qa3.x, kb.x, 1.f)), acc3);
        acc3 = fmaf(v4.y, __builtin_amdgcn_rcpf(fmaf(qa3.y, kb.y, 1.f)), acc3);
        acc3 = fmaf(v4.z, __builtin_amdgcn_rcpf(fmaf(qa3.z, kb.z, 1.f)), acc3);
        acc3 = fmaf(v4.w, __builtin_amdgcn_rcpf(fmaf(qa3.w, kb.w, 1.f)), acc3);
    }

    float* out = spart + (size_t)c * BTS;
    const int base = (b * T + t0) * S + s0 + lane;
    out[base + 0 * S] = fmaf(-2.f, acc0, pv);
    out[base + 1 * S] = fmaf(-2.f, acc1, pv);
    out[base + 2 * S] = fmaf(-2.f, acc2, pv);
    out[base + 3 * S] = fmaf(-2.f, acc3, pv);
}

// ---------------------------------------------------------------------------
// K3: sum 4 partials -> softmax over s -> context = attn @ enc. Block per 4 t.
// ---------------------------------------------------------------------------
__global__ __launch_bounds__(256) void softmax_ctx(
    const float* __restrict__ spart, const float* __restrict__ enc,
    float* __restrict__ out)
{
    __shared__ float attn[4][S];
    __shared__ float red[4];

    const int b  = blockIdx.y;
    const int t0 = blockIdx.x * 4;
    const int tid  = threadIdx.x;
    const int lane = tid & 63;
    const int w    = tid >> 6;

    const float* p0 = spart;
    const float* p1 = spart + BTS;
    const float* p2 = spart + 2 * (size_t)BTS;
    const float* p3 = spart + 3 * (size_t)BTS;

    for (int tt = 0; tt < 4; ++tt) {
        const size_t roff = (size_t)(b * T + t0 + tt) * S;
        float s1 = p0[roff + tid]       + p1[roff + tid]
                 + p2[roff + tid]       + p3[roff + tid];
        float s2 = p0[roff + tid + 256] + p1[roff + tid + 256]
                 + p2[roff + tid + 256] + p3[roff + tid + 256];

        // block max
        float m = fmaxf(s1, s2);
        #pragma unroll
        for (int off = 32; off; off >>= 1) m = fmaxf(m, __shfl_xor(m, off));
        if (lane == 0) red[w] = m;
        __syncthreads();
        m = fmaxf(fmaxf(red[0], red[1]), fmaxf(red[2], red[3]));
        __syncthreads();

        float e1 = __expf(s1 - m);
        float e2 = __expf(s2 - m);

        // block sum
        float sum = e1 + e2;
        #pragma unroll
        for (int off = 32; off; off >>= 1) sum += __shfl_xor(sum, off);
        if (lane == 0) red[w] = sum;
        __syncthreads();
        sum = red[0] + red[1] + red[2] + red[3];
        __syncthreads();

        float inv = __builtin_amdgcn_rcpf(sum);
        attn[tt][tid]       = e1 * inv;
        attn[tt][tid + 256] = e2 * inv;
    }
    __syncthreads();

    float c0[4] = {0.f, 0.f, 0.f, 0.f};
    float c1[4] = {0.f, 0.f, 0.f, 0.f};
    for (int s = 0; s < S; ++s) {
        float e0 = enc[(size_t)(b * S + s) * H + tid];
        float e1 = enc[(size_t)(b * S + s) * H + tid + 256];
        #pragma unroll
        for (int tt = 0; tt < 4; ++tt) {
            float a = attn[tt][s];
            c0[tt] += a * e0;
            c1[tt] += a * e1;
        }
    }
    #pragma unroll
    for (int tt = 0; tt < 4; ++tt) {
        out[(size_t)(b * T + t0 + tt) * H + tid]       = c0[tt];
        out[(size_t)(b * T + t0 + tt) * H + tid + 256] = c1[tt];
    }
}

extern "C" void kernel_launch(void* const* d_in, const int* in_sizes, int n_in,
                              void* d_out, int out_size, void* d_ws, size_t ws_size,
                              hipStream_t stream) {
    const float* dh  = (const float*)d_in[0];
    const float* enc = (const float*)d_in[1];
    const float* W1  = (const float*)d_in[2];
    const float* b1  = (const float*)d_in[3];
    const float* W2  = (const float*)d_in[4];
    const float* b2  = (const float*)d_in[5];
    const float* V   = (const float*)d_in[6];
    const float* bV  = (const float*)d_in[7];

    float* ws    = (float*)d_ws;
    float* abuf  = ws;                                   // B*T*H = 524288  (exp2 q')
    float* bT4   = abuf + (size_t)B * T * H;             // B*S*H = 1048576 (exp2 k', [b][h/4][s][4])
    float* spart = bT4 + (size_t)B * S * H;              // 4 * B*T*S = 2097152

    dim3 blk(256);
    proj_gemm   <<<dim3(8, 48),    blk, 0, stream>>>(dh, enc, W1, b1, W2, b2, abuf, bT4);
    score_kernel<<<dim3(8, 16, 16), blk, 0, stream>>>(abuf, bT4, V, bV, spart);
    softmax_ctx <<<dim3(64, 4),    blk, 0, stream>>>(spart, enc, (float*)d_out);
}

// Round 5
// 102.553 us; speedup vs baseline: 1.5477x; 1.0689x over previous
//
#include <hip/hip_runtime.h>

#define B 4
#define T 256
#define S 512
#define H 512
#define H4 (H/4)          // 128
#define BTS (B*T*S)       // 524288
#define PS (3072*512)     // split-K partial stride (rows 0..1023 q, 1024..3071 k)

// 2 * log2(e): projections are prescaled so exp2 replaces exp.
#define PRESCALE 2.8853900817779268f

#if __has_builtin(__builtin_amdgcn_exp2f)
#define EXP2(x) __builtin_amdgcn_exp2f(x)
#else
#define EXP2(x) exp2f(x)
#endif

// ---------------------------------------------------------------------------
// K1a: split-K projection GEMM (no bias, no epilogue).
//   part[kz][m][n] = sum_{k in chunk kz} A[m,k]*W[n,k]
// Tile 128m x 64n, micro 8x4 per thread (1.5 B LDS-read per FMA), BK=16.
// Grid (8 nTiles, 24 mTiles, 4 kz) = 768 blocks -> 3 blocks/CU.
// ---------------------------------------------------------------------------
__global__ __launch_bounds__(256) void proj_split(
    const float* __restrict__ dh, const float* __restrict__ enc,
    const float* __restrict__ W1, const float* __restrict__ W2,
    float* __restrict__ part)
{
    __shared__ float As[16][128];
    __shared__ float Ws[16][64];

    const int tid   = threadIdx.x;
    const int n0    = blockIdx.x * 64;
    const int mTile = blockIdx.y;          // 0..23
    const int kz    = blockIdx.z;          // 0..3

    const float* A; const float* W; int mbase;
    if (mTile < 8) { A = dh;  W = W1; mbase = mTile * 128; }
    else           { A = enc; W = W2; mbase = (mTile - 8) * 128; }

    const int lr = tid >> 1;            // A staging row 0..127
    const int lh = (tid & 1) * 8;       // A staging k-offset 0/8
    const int wr = tid >> 2;            // W staging row 0..63
    const int wk = (tid & 3) * 4;       // W staging k-offset 0..12

    const int tm = tid >> 4;            // micro rows tm*8..+7
    const int tn = tid & 15;            // micro cols tn*4..+3

    float acc[8][4] = {};

    const int kend = kz * 128 + 128;
    for (int kc = kz * 128; kc < kend; kc += 16) {
        float4 a0 = *(const float4*)&A[(size_t)(mbase + lr) * H + kc + lh];
        float4 a1 = *(const float4*)&A[(size_t)(mbase + lr) * H + kc + lh + 4];
        float4 w0 = *(const float4*)&W[(size_t)(n0 + wr) * H + kc + wk];
        __syncthreads();
        As[lh + 0][lr] = a0.x; As[lh + 1][lr] = a0.y;
        As[lh + 2][lr] = a0.z; As[lh + 3][lr] = a0.w;
        As[lh + 4][lr] = a1.x; As[lh + 5][lr] = a1.y;
        As[lh + 6][lr] = a1.z; As[lh + 7][lr] = a1.w;
        Ws[wk + 0][wr] = w0.x; Ws[wk + 1][wr] = w0.y;
        Ws[wk + 2][wr] = w0.z; Ws[wk + 3][wr] = w0.w;
        __syncthreads();
        #pragma unroll
        for (int kk = 0; kk < 16; ++kk) {
            float4 am0 = *(const float4*)&As[kk][tm * 8];
            float4 am1 = *(const float4*)&As[kk][tm * 8 + 4];
            float4 wn  = *(const float4*)&Ws[kk][tn * 4];
            float a8[8] = {am0.x, am0.y, am0.z, am0.w, am1.x, am1.y, am1.z, am1.w};
            float w4[4] = {wn.x, wn.y, wn.z, wn.w};
            #pragma unroll
            for (int i = 0; i < 8; ++i)
                #pragma unroll
                for (int j = 0; j < 4; ++j)
                    acc[i][j] += a8[i] * w4[j];
        }
    }

    float* outp = part + (size_t)kz * PS;
    #pragma unroll
    for (int i = 0; i < 8; ++i) {
        const int grow = mTile * 128 + tm * 8 + i;
        *(float4*)&outp[(size_t)grow * 512 + n0 + tn * 4] =
            make_float4(acc[i][0], acc[i][1], acc[i][2], acc[i][3]);
    }
}

// ---------------------------------------------------------------------------
// K1b: epilogue. sum 4 partials + bias -> exp2(min(x*PRESCALE,126)).
// Blocks 0..127:   q rows (0..1023) -> abuf row-major.
// Blocks 128..383: k rows in 64x64 tiles -> bT4[b][h/4][s][4] via LDS
//                  transpose (stride 65, scalar LDS ops: conflict-free).
// ---------------------------------------------------------------------------
__global__ __launch_bounds__(256) void exp_trans(
    const float* __restrict__ part,
    const float* __restrict__ b1, const float* __restrict__ b2,
    float* __restrict__ abuf, float* __restrict__ bT4)
{
    const int tid = threadIdx.x;

    if (blockIdx.x < 128) {
        const float4* p0 = (const float4*)part;
        const float4* p1 = (const float4*)(part + (size_t)PS);
        const float4* p2 = (const float4*)(part + 2 * (size_t)PS);
        const float4* p3 = (const float4*)(part + 3 * (size_t)PS);
        #pragma unroll
        for (int j = 0; j < 4; ++j) {
            const int f = blockIdx.x * 256 + tid + j * 32768;
            float4 v0 = p0[f], v1 = p1[f], v2 = p2[f], v3 = p3[f];
            float4 bv = *(const float4*)&b1[(f & 127) * 4];
            float4 o;
            o.x = EXP2(fminf((v0.x + v1.x + v2.x + v3.x + bv.x) * PRESCALE, 126.f));
            o.y = EXP2(fminf((v0.y + v1.y + v2.y + v3.y + bv.y) * PRESCALE, 126.f));
            o.z = EXP2(fminf((v0.z + v1.z + v2.z + v3.z + bv.z) * PRESCALE, 126.f));
            o.w = EXP2(fminf((v0.w + v1.w + v2.w + v3.w + bv.w) * PRESCALE, 126.f));
            ((float4*)abuf)[f] = o;
        }
    } else {
        __shared__ float TT[64][65];
        const int kb   = blockIdx.x - 128;
        const int rt   = kb >> 3;          // 0..31 (row tile of 64 k-rows)
        const int ct   = kb & 7;           // 0..7  (col tile of 64 h)
        const int r16  = tid >> 4;         // 0..15
        const int col4 = tid & 15;         // float4 col within tile

        #pragma unroll
        for (int jj = 0; jj < 4; ++jj) {
            const int r = r16 + jj * 16;                 // 0..63
            const size_t grow = 1024 + (size_t)rt * 64 + r;
            const size_t off  = grow * 512 + ct * 64 + col4 * 4;
            float4 v0 = *(const float4*)&part[off];
            float4 v1 = *(const float4*)&part[off + (size_t)PS];
            float4 v2 = *(const float4*)&part[off + 2 * (size_t)PS];
            float4 v3 = *(const float4*)&part[off + 3 * (size_t)PS];
            float4 bv = *(const float4*)&b2[ct * 64 + col4 * 4];
            TT[r][col4 * 4 + 0] = EXP2(fminf((v0.x + v1.x + v2.x + v3.x + bv.x) * PRESCALE, 126.f));
            TT[r][col4 * 4 + 1] = EXP2(fminf((v0.y + v1.y + v2.y + v3.y + bv.y) * PRESCALE, 126.f));
            TT[r][col4 * 4 + 2] = EXP2(fminf((v0.z + v1.z + v2.z + v3.z + bv.z) * PRESCALE, 126.f));
            TT[r][col4 * 4 + 3] = EXP2(fminf((v0.w + v1.w + v2.w + v3.w + bv.w) * PRESCALE, 126.f));
        }
        __syncthreads();

        const int sl = tid & 63;           // s within tile
        const int hq = tid >> 6;           // 0..3
        const int gs = rt * 64 + sl;       // k row 0..2047
        const int bb = gs >> 9;
        const int ss = gs & 511;
        #pragma unroll
        for (int jj = 0; jj < 4; ++jj) {
            const int hl = hq * 16 + jj * 4;
            float4 v = make_float4(TT[sl][hl + 0], TT[sl][hl + 1],
                                   TT[sl][hl + 2], TT[sl][hl + 3]);
            const int h = ct * 64 + hl;
            *(float4*)&bT4[((size_t)(bb * H4 + (h >> 2)) * S + ss) * 4] = v;
        }
    }
}

// ---------------------------------------------------------------------------
// K2: score partials.  full score = sum_h V[h] - 2*sum_h V[h]*rcp(a*b+1) + bV
// ---------------------------------------------------------------------------
__global__ __launch_bounds__(256) void score_kernel(
    const float* __restrict__ abuf, const float* __restrict__ bT4,
    const float* __restrict__ Vp, const float* __restrict__ bVp,
    float* __restrict__ spart)
{
    const int tid  = threadIdx.x;
    const int lane = tid & 63;
    const int w    = tid >> 6;
    const int b    = blockIdx.z >> 2;
    const int c    = blockIdx.z & 3;           // h-chunk
    const int t0   = blockIdx.y * 16 + w * 4;
    const int s0   = blockIdx.x * 64;
    const int h0   = c * 128;

    float pv = Vp[h0 + lane] + Vp[h0 + 64 + lane];
    #pragma unroll
    for (int off = 32; off; off >>= 1) pv += __shfl_xor(pv, off);
    if (c == 0) pv += bVp[0];

    const float* a0 = abuf + __builtin_amdgcn_readfirstlane((b * T + t0 + 0) * H);
    const float* a1 = abuf + __builtin_amdgcn_readfirstlane((b * T + t0 + 1) * H);
    const float* a2 = abuf + __builtin_amdgcn_readfirstlane((b * T + t0 + 2) * H);
    const float* a3 = abuf + __builtin_amdgcn_readfirstlane((b * T + t0 + 3) * H);

    const float4* bp = (const float4*)bT4 + (size_t)(b * H4 + (h0 >> 2)) * S + s0 + lane;

    float acc0 = 0.f, acc1 = 0.f, acc2 = 0.f, acc3 = 0.f;

    #pragma unroll 4
    for (int h4 = 0; h4 < 32; ++h4) {
        const int h = h0 + h4 * 4;
        float4 kb = bp[(size_t)h4 * S];
        float4 v4  = *(const float4*)&Vp[h];
        float4 qa0 = *(const float4*)&a0[h];
        float4 qa1 = *(const float4*)&a1[h];
        float4 qa2 = *(const float4*)&a2[h];
        float4 qa3 = *(const float4*)&a3[h];

        acc0 = fmaf(v4.x, __builtin_amdgcn_rcpf(fmaf(qa0.x, kb.x, 1.f)), acc0);
        acc0 = fmaf(v4.y, __builtin_amdgcn_rcpf(fmaf(qa0.y, kb.y, 1.f)), acc0);
        acc0 = fmaf(v4.z, __builtin_amdgcn_rcpf(fmaf(qa0.z, kb.z, 1.f)), acc0);
        acc0 = fmaf(v4.w, __builtin_amdgcn_rcpf(fmaf(qa0.w, kb.w, 1.f)), acc0);

        acc1 = fmaf(v4.x, __builtin_amdgcn_rcpf(fmaf(qa1.x, kb.x, 1.f)), acc1);
        acc1 = fmaf(v4.y, __builtin_amdgcn_rcpf(fmaf(qa1.y, kb.y, 1.f)), acc1);
        acc1 = fmaf(v4.z, __builtin_amdgcn_rcpf(fmaf(qa1.z, kb.z, 1.f)), acc1);
        acc1 = fmaf(v4.w, __builtin_amdgcn_rcpf(fmaf(qa1.w, kb.w, 1.f)), acc1);

        acc2 = fmaf(v4.x, __builtin_amdgcn_rcpf(fmaf(qa2.x, kb.x, 1.f)), acc2);
        acc2 = fmaf(v4.y, __builtin_amdgcn_rcpf(fmaf(qa2.y, kb.y, 1.f)), acc2);
        acc2 = fmaf(v4.z, __builtin_amdgcn_rcpf(fmaf(qa2.z, kb.z, 1.f)), acc2);
        acc2 = fmaf(v4.w, __builtin_amdgcn_rcpf(fmaf(qa2.w, kb.w, 1.f)), acc2);

        acc3 = fmaf(v4.x, __builtin_amdgcn_rcpf(fmaf(qa3.x, kb.x, 1.f)), acc3);
        acc3 = fmaf(v4.y, __builtin_amdgcn_rcpf(fmaf(qa3.y, kb.y, 1.f)), acc3);
        acc3 = fmaf(v4.z, __builtin_amdgcn_rcpf(fmaf(qa3.z, kb.z, 1.f)), acc3);
        acc3 = fmaf(v4.w, __builtin_amdgcn_rcpf(fmaf(qa3.w, kb.w, 1.f)), acc3);
    }

    float* out = spart + (size_t)c * BTS;
    const int base = (b * T + t0) * S + s0 + lane;
    out[base + 0 * S] = fmaf(-2.f, acc0, pv);
    out[base + 1 * S] = fmaf(-2.f, acc1, pv);
    out[base + 2 * S] = fmaf(-2.f, acc2, pv);
    out[base + 3 * S] = fmaf(-2.f, acc3, pv);
}

// ---------------------------------------------------------------------------
// K3: sum 4 partials -> softmax over s -> context = attn @ enc. Block per 4 t.
// ---------------------------------------------------------------------------
__global__ __launch_bounds__(256) void softmax_ctx(
    const float* __restrict__ spart, const float* __restrict__ enc,
    float* __restrict__ out)
{
    __shared__ float attn[4][S];
    __shared__ float red[4];

    const int b  = blockIdx.y;
    const int t0 = blockIdx.x * 4;
    const int tid  = threadIdx.x;
    const int lane = tid & 63;
    const int w    = tid >> 6;

    const float* p0 = spart;
    const float* p1 = spart + (size_t)BTS;
    const float* p2 = spart + 2 * (size_t)BTS;
    const float* p3 = spart + 3 * (size_t)BTS;

    for (int tt = 0; tt < 4; ++tt) {
        const size_t roff = (size_t)(b * T + t0 + tt) * S;
        float s1 = p0[roff + tid]       + p1[roff + tid]
                 + p2[roff + tid]       + p3[roff + tid];
        float s2 = p0[roff + tid + 256] + p1[roff + tid + 256]
                 + p2[roff + tid + 256] + p3[roff + tid + 256];

        float m = fmaxf(s1, s2);
        #pragma unroll
        for (int off = 32; off; off >>= 1) m = fmaxf(m, __shfl_xor(m, off));
        if (lane == 0) red[w] = m;
        __syncthreads();
        m = fmaxf(fmaxf(red[0], red[1]), fmaxf(red[2], red[3]));
        __syncthreads();

        float e1 = __expf(s1 - m);
        float e2 = __expf(s2 - m);

        float sum = e1 + e2;
        #pragma unroll
        for (int off = 32; off; off >>= 1) sum += __shfl_xor(sum, off);
        if (lane == 0) red[w] = sum;
        __syncthreads();
        sum = red[0] + red[1] + red[2] + red[3];
        __syncthreads();

        float inv = __builtin_amdgcn_rcpf(sum);
        attn[tt][tid]       = e1 * inv;
        attn[tt][tid + 256] = e2 * inv;
    }
    __syncthreads();

    float c0[4] = {0.f, 0.f, 0.f, 0.f};
    float c1[4] = {0.f, 0.f, 0.f, 0.f};
    for (int s = 0; s < S; ++s) {
        float e0 = enc[(size_t)(b * S + s) * H + tid];
        float e1 = enc[(size_t)(b * S + s) * H + tid + 256];
        #pragma unroll
        for (int tt = 0; tt < 4; ++tt) {
            float a = attn[tt][s];
            c0[tt] += a * e0;
            c1[tt] += a * e1;
        }
    }
    #pragma unroll
    for (int tt = 0; tt < 4; ++tt) {
        out[(size_t)(b * T + t0 + tt) * H + tid]       = c0[tt];
        out[(size_t)(b * T + t0 + tt) * H + tid + 256] = c1[tt];
    }
}

extern "C" void kernel_launch(void* const* d_in, const int* in_sizes, int n_in,
                              void* d_out, int out_size, void* d_ws, size_t ws_size,
                              hipStream_t stream) {
    const float* dh  = (const float*)d_in[0];
    const float* enc = (const float*)d_in[1];
    const float* W1  = (const float*)d_in[2];
    const float* b1  = (const float*)d_in[3];
    const float* W2  = (const float*)d_in[4];
    const float* b2  = (const float*)d_in[5];
    const float* V   = (const float*)d_in[6];
    const float* bV  = (const float*)d_in[7];

    float* ws    = (float*)d_ws;
    float* part  = ws;                          // 4*PS = 6291456 floats (25.2 MB)
    float* spart = ws;                          // aliases part (dead by K2)
    float* abuf  = ws + 4 * (size_t)PS;         // B*T*H = 524288
    float* bT4   = abuf + (size_t)B * T * H;    // B*S*H = 1048576

    dim3 blk(256);
    proj_split  <<<dim3(8, 24, 4),  blk, 0, stream>>>(dh, enc, W1, W2, part);
    exp_trans   <<<dim3(384),       blk, 0, stream>>>(part, b1, b2, abuf, bT4);
    score_kernel<<<dim3(8, 16, 16), blk, 0, stream>>>(abuf, bT4, V, bV, spart);
    softmax_ctx <<<dim3(64, 4),     blk, 0, stream>>>(spart, enc, (float*)d_out);
}